// Round 1
// baseline (1501.417 us; speedup 1.0000x reference)
//
#include <hip/hip_runtime.h>

#define N_NODES 100000
#define N_EDGES 1600000
#define N_GRAPHS 256

__device__ __forceinline__ float lrelu(float v) { return v > 0.f ? v : 0.01f * v; }

// ---- T[N,dout] = X[N,din] @ W[din,dout], LDS-tiled, 64 nodes/block ----
__global__ void matmul_kernel(const float* __restrict__ X, const float* __restrict__ W,
                              float* __restrict__ T, int N, int din, int dout) {
    extern __shared__ float lds[];
    float* xs = lds;              // 64*din
    float* wsm = lds + 64 * din;  // din*dout
    const int n0 = blockIdx.x * 64;
    for (int i = threadIdx.x; i < din * dout; i += 256) wsm[i] = W[i];
    for (int i = threadIdx.x; i < 64 * din; i += 256) {
        int r = i / din, c = i - r * din;
        int node = n0 + r;
        xs[i] = (node < N) ? X[(size_t)node * din + c] : 0.f;
    }
    __syncthreads();
    for (int o = threadIdx.x; o < 64 * dout; o += 256) {
        int r = o / dout, j = o - r * dout;
        int node = n0 + r;
        if (node < N) {
            float acc = 0.f;
            const float* xr = xs + r * din;
            for (int k = 0; k < din; ++k) acc = fmaf(xr[k], wsm[k * dout + j], acc);
            T[(size_t)node * dout + j] = acc;
        }
    }
}

// ---- scatter: A[dst[e], j] += T[src[e], j] ----
template <int DOUT>
__global__ void scatter_kernel(const float* __restrict__ T, const int* __restrict__ src,
                               const int* __restrict__ dst, float* __restrict__ A) {
    int i = blockIdx.x * 256 + threadIdx.x;
    if (i >= N_EDGES * DOUT) return;
    int e = i / DOUT;
    int j = i - e * DOUT;
    atomicAdd(&A[(size_t)dst[e] * DOUT + j], T[(size_t)src[e] * DOUT + j]);
}

// ---- A[i,j] = act(A[i,j] + b[j]) ----
template <int DOUT, bool RELU>
__global__ void bias_act_kernel(float* __restrict__ A, const float* __restrict__ b) {
    int i = blockIdx.x * 256 + threadIdx.x;
    if (i >= N_NODES * DOUT) return;
    int j = i % DOUT;
    float v = A[i] + b[j];
    A[i] = RELU ? lrelu(v) : v;
}

// ---- BN stats: one block per feature (50 blocks), deterministic tree reduce ----
__global__ void bn_stats_kernel(const float* __restrict__ H, float* __restrict__ mu,
                                float* __restrict__ rsig) {
    __shared__ float s1[256], s2[256];
    int j = blockIdx.x;
    float s = 0.f, ss = 0.f;
    for (int i = threadIdx.x; i < N_NODES; i += 256) {
        float v = H[(size_t)i * 50 + j];
        s += v;
        ss += v * v;
    }
    s1[threadIdx.x] = s;
    s2[threadIdx.x] = ss;
    __syncthreads();
    for (int off = 128; off > 0; off >>= 1) {
        if (threadIdx.x < off) {
            s1[threadIdx.x] += s1[threadIdx.x + off];
            s2[threadIdx.x] += s2[threadIdx.x + off];
        }
        __syncthreads();
    }
    if (threadIdx.x == 0) {
        float m = s1[0] / (float)N_NODES;
        float var = s2[0] / (float)N_NODES - m * m;
        mu[j] = m;
        rsig[j] = rsqrtf(fmaxf(var, 0.f) + 1e-5f);
    }
}

// ---- BN-apply + lrelu + global_add_pool ----
__global__ void pool_kernel(const float* __restrict__ H, const int* __restrict__ batch,
                            const float* __restrict__ mu, const float* __restrict__ rsig,
                            const float* __restrict__ gamma, const float* __restrict__ beta,
                            float* __restrict__ G) {
    int i = blockIdx.x * 256 + threadIdx.x;
    if (i >= N_NODES * 50) return;
    int node = i / 50;
    int j = i - node * 50;
    float v = (H[i] - mu[j]) * rsig[j] * gamma[j] + beta[j];
    v = lrelu(v);
    atomicAdd(&G[(size_t)batch[node] * 50 + j], v);
}

// ---- MLP head: one thread per graph ----
__global__ void mlp_kernel(const float* __restrict__ G,
                           const float* __restrict__ fc1W, const float* __restrict__ fc1b,
                           const float* __restrict__ fc2W, const float* __restrict__ fc2b,
                           const float* __restrict__ fc3W, const float* __restrict__ fc3b,
                           float* __restrict__ out) {
    int g = blockIdx.x * blockDim.x + threadIdx.x;
    if (g >= N_GRAPHS) return;
    float a[50];
#pragma unroll
    for (int k = 0; k < 50; ++k) a[k] = G[g * 50 + k];
    float h1[30];
#pragma unroll
    for (int j = 0; j < 30; ++j) {
        float acc = fc1b[j];
#pragma unroll
        for (int k = 0; k < 50; ++k) acc = fmaf(a[k], fc1W[k * 30 + j], acc);
        h1[j] = lrelu(acc);
    }
    float h2[20];
#pragma unroll
    for (int j = 0; j < 20; ++j) {
        float acc = fc2b[j];
#pragma unroll
        for (int k = 0; k < 30; ++k) acc = fmaf(h1[k], fc2W[k * 20 + j], acc);
        h2[j] = lrelu(acc);
    }
    float z0 = fc3b[0], z1 = fc3b[1];
#pragma unroll
    for (int k = 0; k < 20; ++k) {
        z0 = fmaf(h2[k], fc3W[k * 2 + 0], z0);
        z1 = fmaf(h2[k], fc3W[k * 2 + 1], z1);
    }
    float m = fmaxf(z0, z1);
    float lse = m + logf(expf(z0 - m) + expf(z1 - m));
    out[g * 2 + 0] = z0 - lse;
    out[g * 2 + 1] = z1 - lse;
}

extern "C" void kernel_launch(void* const* d_in, const int* in_sizes, int n_in,
                              void* d_out, int out_size, void* d_ws, size_t ws_size,
                              hipStream_t stream) {
    const float* x     = (const float*)d_in[0];
    const int*   ei    = (const int*)d_in[1];
    const int*   batch = (const int*)d_in[2];
    const float* W1 = (const float*)d_in[3];  const float* b1 = (const float*)d_in[4];
    const float* W2 = (const float*)d_in[5];  const float* b2 = (const float*)d_in[6];
    const float* W3 = (const float*)d_in[7];  const float* b3 = (const float*)d_in[8];
    const float* W4 = (const float*)d_in[9];  const float* b4 = (const float*)d_in[10];
    const float* bng = (const float*)d_in[11]; const float* bnb = (const float*)d_in[12];
    const float* fc1W = (const float*)d_in[13]; const float* fc1b = (const float*)d_in[14];
    const float* fc2W = (const float*)d_in[15]; const float* fc2b = (const float*)d_in[16];
    const float* fc3W = (const float*)d_in[17]; const float* fc3b = (const float*)d_in[18];

    const int* src = ei;
    const int* dst = ei + N_EDGES;

    float* w    = (float*)d_ws;
    float* bufA = w;                    // 100000*64 = 6.4M floats
    float* bufB = w + 6400000;
    float* bufC = w + 12800000;
    float* mu   = w + 19200000;         // 64
    float* rsig = mu + 64;              // 64
    float* G    = rsig + 64;            // 256*50

    dim3 blk(256);
    const int mmBlocks = (N_NODES + 63) / 64;

    // ---- Layer 1: x[100000,128] @ W1[128,16] ----
    hipLaunchKernelGGL(matmul_kernel, dim3(mmBlocks), blk, (64 * 128 + 128 * 16) * 4, stream,
                       x, W1, bufA, N_NODES, 128, 16);
    hipMemsetAsync(bufB, 0, (size_t)N_NODES * 16 * 4, stream);
    scatter_kernel<16><<<(N_EDGES * 16 + 255) / 256, blk, 0, stream>>>(bufA, src, dst, bufB);
    bias_act_kernel<16, true><<<(N_NODES * 16 + 255) / 256, blk, 0, stream>>>(bufB, b1);

    // ---- Layer 2: [100000,16] @ W2[16,32] ----
    hipLaunchKernelGGL(matmul_kernel, dim3(mmBlocks), blk, (64 * 16 + 16 * 32) * 4, stream,
                       bufB, W2, bufA, N_NODES, 16, 32);
    hipMemsetAsync(bufC, 0, (size_t)N_NODES * 32 * 4, stream);
    scatter_kernel<32><<<(N_EDGES * 32 + 255) / 256, blk, 0, stream>>>(bufA, src, dst, bufC);
    bias_act_kernel<32, true><<<(N_NODES * 32 + 255) / 256, blk, 0, stream>>>(bufC, b2);

    // ---- Layer 3: [100000,32] @ W3[32,64] ----
    hipLaunchKernelGGL(matmul_kernel, dim3(mmBlocks), blk, (64 * 32 + 32 * 64) * 4, stream,
                       bufC, W3, bufA, N_NODES, 32, 64);
    hipMemsetAsync(bufB, 0, (size_t)N_NODES * 64 * 4, stream);
    scatter_kernel<64><<<(N_EDGES * 64 + 255) / 256, blk, 0, stream>>>(bufA, src, dst, bufB);
    bias_act_kernel<64, true><<<(N_NODES * 64 + 255) / 256, blk, 0, stream>>>(bufB, b3);

    // ---- Layer 4: [100000,64] @ W4[64,50], bias only (no lrelu) ----
    hipLaunchKernelGGL(matmul_kernel, dim3(mmBlocks), blk, (64 * 64 + 64 * 50) * 4, stream,
                       bufB, W4, bufA, N_NODES, 64, 50);
    hipMemsetAsync(bufC, 0, (size_t)N_NODES * 50 * 4, stream);
    scatter_kernel<50><<<(N_EDGES * 50 + 255) / 256, blk, 0, stream>>>(bufA, src, dst, bufC);
    bias_act_kernel<50, false><<<(N_NODES * 50 + 255) / 256, blk, 0, stream>>>(bufC, b4);

    // ---- BatchNorm stats over nodes ----
    bn_stats_kernel<<<50, blk, 0, stream>>>(bufC, mu, rsig);

    // ---- BN apply + lrelu + pool ----
    hipMemsetAsync(G, 0, (size_t)N_GRAPHS * 50 * 4, stream);
    pool_kernel<<<(N_NODES * 50 + 255) / 256, blk, 0, stream>>>(bufC, batch, mu, rsig, bng, bnb, G);

    // ---- MLP head + log_softmax ----
    mlp_kernel<<<1, 256, 0, stream>>>(G, fc1W, fc1b, fc2W, fc2b, fc3W, fc3b, (float*)d_out);
}

// Round 3
// 928.612 us; speedup vs baseline: 1.6168x; 1.6168x over previous
//
#include <hip/hip_runtime.h>

#define N_NODES 100000
#define N_EDGES 1600000
#define N_GRAPHS 256
#define NCHUNKS ((N_NODES + 255) / 256)   // 391

__device__ __forceinline__ float lrelu(float v) { return v > 0.f ? v : 0.01f * v; }

// ============ CSR build ============
__global__ void degree_kernel(const int* __restrict__ dst, int* __restrict__ deg) {
    int e = blockIdx.x * 256 + threadIdx.x;
    if (e < N_EDGES) atomicAdd(&deg[dst[e]], 1);
}

// Per-256-chunk inclusive scan of deg -> base[i+1]; chunk totals -> chunkSum
__global__ void scan_chunks_kernel(const int* __restrict__ deg, int* __restrict__ base,
                                   int* __restrict__ chunkSum) {
    __shared__ int s[256];
    int t = threadIdx.x;
    int i = blockIdx.x * 256 + t;
    int v = (i < N_NODES) ? deg[i] : 0;
    s[t] = v;
    __syncthreads();
    for (int off = 1; off < 256; off <<= 1) {
        int add = (t >= off) ? s[t - off] : 0;
        __syncthreads();
        s[t] += add;
        __syncthreads();
    }
    if (i < N_NODES) base[i + 1] = s[t];
    if (t == 255) chunkSum[blockIdx.x] = s[255];
    if (i == 0) base[0] = 0;
}

// Single-block inclusive scan of chunkSum (NCHUNKS <= 512)
__global__ void scan_tops_kernel(int* __restrict__ chunkSum) {
    __shared__ int s[512];
    int t = threadIdx.x;
    s[t] = (t < NCHUNKS) ? chunkSum[t] : 0;
    __syncthreads();
    for (int off = 1; off < 512; off <<= 1) {
        int add = (t >= off) ? s[t - off] : 0;
        __syncthreads();
        s[t] += add;
        __syncthreads();
    }
    if (t < NCHUNKS) chunkSum[t] = s[t];
}

__global__ void add_offsets_kernel(int* __restrict__ base, const int* __restrict__ chunkSum) {
    int i = blockIdx.x * 256 + threadIdx.x;
    if (i < N_NODES) {
        int b = i / 256;
        if (b > 0) base[i + 1] += chunkSum[b - 1];
    }
}

__global__ void fill_adj_kernel(const int* __restrict__ src, const int* __restrict__ dst,
                                const int* __restrict__ base, int* __restrict__ cursor,
                                int* __restrict__ adj) {
    int e = blockIdx.x * 256 + threadIdx.x;
    if (e < N_EDGES) {
        int d = dst[e];
        int pos = atomicAdd(&cursor[d], 1);
        adj[base[d] + pos] = src[e];
    }
}

// ============ dense matmul (small weights), optional bias+lrelu epilogue ============
__global__ void matmul_kernel(const float* __restrict__ X, const float* __restrict__ W,
                              float* __restrict__ T, int din, int dout,
                              const float* __restrict__ bias, int relu) {
    extern __shared__ float lds[];
    float* xs = lds;              // 64*din
    float* wsm = lds + 64 * din;  // din*dout
    const int n0 = blockIdx.x * 64;
    for (int i = threadIdx.x; i < din * dout; i += 256) wsm[i] = W[i];
    for (int i = threadIdx.x; i < 64 * din; i += 256) {
        int r = i / din, c = i - r * din;
        int node = n0 + r;
        xs[i] = (node < N_NODES) ? X[(size_t)node * din + c] : 0.f;
    }
    __syncthreads();
    for (int o = threadIdx.x; o < 64 * dout; o += 256) {
        int r = o / dout, j = o - r * dout;
        int node = n0 + r;
        if (node < N_NODES) {
            float acc = 0.f;
            const float* xr = xs + r * din;
            for (int k = 0; k < din; ++k) acc = fmaf(xr[k], wsm[k * dout + j], acc);
            if (bias) acc += bias[j];
            if (relu) acc = lrelu(acc);
            T[(size_t)node * dout + j] = acc;
        }
    }
}

// ============ CSR gather-aggregate: out[i,:] = sum_{e: dst=i} T[src_e,:] ============
template <int DOUT, bool BIAS, bool RELU>
__global__ void gather_agg(const float* __restrict__ T, const int* __restrict__ base,
                           const int* __restrict__ adj, const float* __restrict__ b,
                           float* __restrict__ out) {
    constexpr int LPN = (DOUT <= 16) ? 16 : (DOUT <= 32 ? 32 : 64);
    int gi = blockIdx.x * 256 + threadIdx.x;
    int node = gi / LPN;
    int j = gi & (LPN - 1);
    if (node >= N_NODES) return;
    if (j < DOUT) {
        float acc = 0.f;
        int e0 = base[node], e1 = base[node + 1];
        for (int k = e0; k < e1; ++k) {
            int s = adj[k];
            acc += T[(size_t)s * DOUT + j];
        }
        if (BIAS) acc += b[j];
        if (RELU) acc = lrelu(acc);
        out[(size_t)node * DOUT + j] = acc;
    }
}

// ============ BatchNorm stats: coalesced partial sums ============
__global__ void bn_partial_kernel(const float* __restrict__ H, float* __restrict__ sum,
                                  float* __restrict__ ssum) {
    int tid = threadIdx.x;
    int j = tid % 50;
    int sub = tid / 50;  // 0..4 for tid<250
    float s = 0.f, ss = 0.f;
    if (tid < 250) {
        for (int node = blockIdx.x * 5 + sub; node < N_NODES; node += gridDim.x * 5) {
            float v = H[(size_t)node * 50 + j];
            s += v;
            ss += v * v;
        }
    }
    __shared__ float ls[256], lss[256];
    ls[tid] = s;
    lss[tid] = ss;
    __syncthreads();
    if (tid < 50) {
        float a = ls[tid] + ls[tid + 50] + ls[tid + 100] + ls[tid + 150] + ls[tid + 200];
        float c = lss[tid] + lss[tid + 50] + lss[tid + 100] + lss[tid + 150] + lss[tid + 200];
        atomicAdd(&sum[tid], a);
        atomicAdd(&ssum[tid], c);
    }
}

__global__ void bn_finalize_kernel(const float* __restrict__ sum, const float* __restrict__ ssum,
                                   float* __restrict__ mu, float* __restrict__ rsig) {
    int j = threadIdx.x;
    if (j < 50) {
        float m = sum[j] / (float)N_NODES;
        float var = ssum[j] / (float)N_NODES - m * m;
        mu[j] = m;
        rsig[j] = rsqrtf(fmaxf(var, 0.f) + 1e-5f);
    }
}

// ============ BN apply + lrelu + global_add_pool ============
__global__ void pool_kernel(const float* __restrict__ H, const int* __restrict__ batch,
                            const float* __restrict__ mu, const float* __restrict__ rsig,
                            const float* __restrict__ gamma, const float* __restrict__ beta,
                            float* __restrict__ G) {
    int i = blockIdx.x * 256 + threadIdx.x;
    if (i >= N_NODES * 50) return;
    int node = i / 50;
    int j = i - node * 50;
    float v = (H[i] - mu[j]) * rsig[j] * gamma[j] + beta[j];
    v = lrelu(v);
    atomicAdd(&G[(size_t)batch[node] * 50 + j], v);
}

// ============ MLP head ============
__global__ void mlp_kernel(const float* __restrict__ G,
                           const float* __restrict__ fc1W, const float* __restrict__ fc1b,
                           const float* __restrict__ fc2W, const float* __restrict__ fc2b,
                           const float* __restrict__ fc3W, const float* __restrict__ fc3b,
                           float* __restrict__ out) {
    int g = blockIdx.x * blockDim.x + threadIdx.x;
    if (g >= N_GRAPHS) return;
    float a[50];
#pragma unroll
    for (int k = 0; k < 50; ++k) a[k] = G[g * 50 + k];
    float h1[30];
#pragma unroll
    for (int j = 0; j < 30; ++j) {
        float acc = fc1b[j];
#pragma unroll
        for (int k = 0; k < 50; ++k) acc = fmaf(a[k], fc1W[k * 30 + j], acc);
        h1[j] = lrelu(acc);
    }
    float h2[20];
#pragma unroll
    for (int j = 0; j < 20; ++j) {
        float acc = fc2b[j];
#pragma unroll
        for (int k = 0; k < 30; ++k) acc = fmaf(h1[k], fc2W[k * 20 + j], acc);
        h2[j] = lrelu(acc);
    }
    float z0 = fc3b[0], z1 = fc3b[1];
#pragma unroll
    for (int k = 0; k < 20; ++k) {
        z0 = fmaf(h2[k], fc3W[k * 2 + 0], z0);
        z1 = fmaf(h2[k], fc3W[k * 2 + 1], z1);
    }
    float m = fmaxf(z0, z1);
    float lse = m + logf(expf(z0 - m) + expf(z1 - m));
    out[g * 2 + 0] = z0 - lse;
    out[g * 2 + 1] = z1 - lse;
}

extern "C" void kernel_launch(void* const* d_in, const int* in_sizes, int n_in,
                              void* d_out, int out_size, void* d_ws, size_t ws_size,
                              hipStream_t stream) {
    const float* x     = (const float*)d_in[0];
    const int*   ei    = (const int*)d_in[1];
    const int*   batch = (const int*)d_in[2];
    const float* W1 = (const float*)d_in[3];  const float* b1 = (const float*)d_in[4];
    const float* W2 = (const float*)d_in[5];  const float* b2 = (const float*)d_in[6];
    const float* W3 = (const float*)d_in[7];  const float* b3 = (const float*)d_in[8];
    const float* W4 = (const float*)d_in[9];  const float* b4 = (const float*)d_in[10];
    const float* bng = (const float*)d_in[11]; const float* bnb = (const float*)d_in[12];
    const float* fc1W = (const float*)d_in[13]; const float* fc1b = (const float*)d_in[14];
    const float* fc2W = (const float*)d_in[15]; const float* fc2b = (const float*)d_in[16];
    const float* fc3W = (const float*)d_in[17]; const float* fc3b = (const float*)d_in[18];

    const int* src = ei;
    const int* dst = ei + N_EDGES;

    // ---- workspace layout ----
    char* w = (char*)d_ws;
    float* bufA = (float*)w;                        w += (size_t)6400000 * 4;  // 25.6 MB
    float* bufB = (float*)w;                        w += (size_t)6400000 * 4;  // 25.6 MB
    int*   adj  = (int*)w;                          w += (size_t)N_EDGES * 4;  // 6.4 MB
    int*   deg  = (int*)w;                          w += (size_t)N_NODES * 4;
    int*   cursor = (int*)w;                        w += (size_t)N_NODES * 4;
    int*   base = (int*)w;                          w += (size_t)(N_NODES + 1) * 4;
    int*   chunkSum = (int*)w;                      w += 512 * 4;
    float* bnsum = (float*)w;                       w += 64 * 4;
    float* bnssum = (float*)w;                      w += 64 * 4;
    float* mu   = (float*)w;                        w += 64 * 4;
    float* rsig = (float*)w;                        w += 64 * 4;
    float* G    = (float*)w;                        w += (size_t)N_GRAPHS * 50 * 4;

    dim3 blk(256);
    const int edgeBlocks = (N_EDGES + 255) / 256;
    const int mmBlocks = (N_NODES + 63) / 64;

    // ---- CSR build (by dst) ----
    hipMemsetAsync(deg, 0, (size_t)N_NODES * 4, stream);
    hipMemsetAsync(cursor, 0, (size_t)N_NODES * 4, stream);
    degree_kernel<<<edgeBlocks, blk, 0, stream>>>(dst, deg);
    scan_chunks_kernel<<<NCHUNKS, blk, 0, stream>>>(deg, base, chunkSum);
    scan_tops_kernel<<<1, 512, 0, stream>>>(chunkSum);
    add_offsets_kernel<<<(N_NODES + 255) / 256, blk, 0, stream>>>(base, chunkSum);
    fill_adj_kernel<<<edgeBlocks, blk, 0, stream>>>(src, dst, base, cursor, adj);

    // ---- L1: T = x @ W1 [128->16]; H1 = lrelu(agg(T) + b1) ----
    hipLaunchKernelGGL(matmul_kernel, dim3(mmBlocks), blk, (64 * 128 + 128 * 16) * 4, stream,
                       x, W1, bufA, 128, 16, nullptr, 0);
    gather_agg<16, true, true><<<(N_NODES * 16 + 255) / 256, blk, 0, stream>>>(bufA, base, adj, b1, bufB);

    // ---- L2: S = agg(H1) [16]; H2 = lrelu(S @ W2 + b2) [16->32] ----
    gather_agg<16, false, false><<<(N_NODES * 16 + 255) / 256, blk, 0, stream>>>(bufB, base, adj, nullptr, bufA);
    hipLaunchKernelGGL(matmul_kernel, dim3(mmBlocks), blk, (64 * 16 + 16 * 32) * 4, stream,
                       bufA, W2, bufB, 16, 32, b2, 1);

    // ---- L3: S = agg(H2) [32]; H3 = lrelu(S @ W3 + b3) [32->64] ----
    gather_agg<32, false, false><<<(N_NODES * 32 + 255) / 256, blk, 0, stream>>>(bufB, base, adj, nullptr, bufA);
    hipLaunchKernelGGL(matmul_kernel, dim3(mmBlocks), blk, (64 * 32 + 32 * 64) * 4, stream,
                       bufA, W3, bufB, 32, 64, b3, 1);

    // ---- L4: T = H3 @ W4 [64->50]; H4 = agg(T) + b4 ----
    hipLaunchKernelGGL(matmul_kernel, dim3(mmBlocks), blk, (64 * 64 + 64 * 50) * 4, stream,
                       bufB, W4, bufA, 64, 50, nullptr, 0);
    gather_agg<50, true, false><<<(N_NODES * 64 + 255) / 256, blk, 0, stream>>>(bufA, base, adj, b4, bufB);

    // ---- BatchNorm stats ----
    hipMemsetAsync(bnsum, 0, 128 * 4, stream);
    bn_partial_kernel<<<256, blk, 0, stream>>>(bufB, bnsum, bnssum);
    bn_finalize_kernel<<<1, 64, 0, stream>>>(bnsum, bnssum, mu, rsig);

    // ---- BN apply + lrelu + pool ----
    hipMemsetAsync(G, 0, (size_t)N_GRAPHS * 50 * 4, stream);
    pool_kernel<<<(N_NODES * 50 + 255) / 256, blk, 0, stream>>>(bufB, batch, mu, rsig, bng, bnb, G);

    // ---- MLP head ----
    mlp_kernel<<<1, 256, 0, stream>>>(G, fc1W, fc1b, fc2W, fc2b, fc3W, fc3b, (float*)d_out);
}

// Round 4
// 725.493 us; speedup vs baseline: 2.0695x; 1.2800x over previous
//
#include <hip/hip_runtime.h>

#define N_NODES 100000
#define N_EDGES 1600000
#define N_GRAPHS 256
#define NCHUNKS ((N_NODES + 255) / 256)   // 391

__device__ __forceinline__ float lrelu(float v) { return v > 0.f ? v : 0.01f * v; }

// bf16 storage helpers (RNE)
__device__ __forceinline__ unsigned short f2bf(float f) {
    unsigned int u = __float_as_uint(f);
    return (unsigned short)((u + 0x7FFFu + ((u >> 16) & 1u)) >> 16);
}
__device__ __forceinline__ float bf2f(unsigned short h) {
    return __uint_as_float(((unsigned int)h) << 16);
}

// ============ CSR build ============
__global__ void degree_kernel(const int* __restrict__ dst, int* __restrict__ deg) {
    int e = blockIdx.x * 256 + threadIdx.x;
    if (e < N_EDGES) atomicAdd(&deg[dst[e]], 1);
}

__global__ void scan_chunks_kernel(const int* __restrict__ deg, int* __restrict__ base,
                                   int* __restrict__ chunkSum) {
    __shared__ int s[256];
    int t = threadIdx.x;
    int i = blockIdx.x * 256 + t;
    int v = (i < N_NODES) ? deg[i] : 0;
    s[t] = v;
    __syncthreads();
    for (int off = 1; off < 256; off <<= 1) {
        int add = (t >= off) ? s[t - off] : 0;
        __syncthreads();
        s[t] += add;
        __syncthreads();
    }
    if (i < N_NODES) base[i + 1] = s[t];
    if (t == 255) chunkSum[blockIdx.x] = s[255];
    if (i == 0) base[0] = 0;
}

__global__ void scan_tops_kernel(int* __restrict__ chunkSum) {
    __shared__ int s[512];
    int t = threadIdx.x;
    s[t] = (t < NCHUNKS) ? chunkSum[t] : 0;
    __syncthreads();
    for (int off = 1; off < 512; off <<= 1) {
        int add = (t >= off) ? s[t - off] : 0;
        __syncthreads();
        s[t] += add;
        __syncthreads();
    }
    if (t < NCHUNKS) chunkSum[t] = s[t];
}

__global__ void add_offsets_kernel(int* __restrict__ base, const int* __restrict__ chunkSum) {
    int i = blockIdx.x * 256 + threadIdx.x;
    if (i < N_NODES) {
        int b = i / 256;
        if (b > 0) base[i + 1] += chunkSum[b - 1];
    }
}

__global__ void fill_adj_kernel(const int* __restrict__ src, const int* __restrict__ dst,
                                const int* __restrict__ base, int* __restrict__ cursor,
                                int* __restrict__ adj) {
    int e = blockIdx.x * 256 + threadIdx.x;
    if (e < N_EDGES) {
        int d = dst[e];
        int pos = atomicAdd(&cursor[d], 1);
        adj[base[d] + pos] = src[e];
    }
}

// ============ matmul: X[N,DIN] @ W[DIN,DOUT] -> T bf16, optional bias+lrelu ============
template <int DIN, int DOUT, bool IN_F32, bool BIAS, bool RELU>
__global__ void matmul_bf16(const void* __restrict__ Xv, const float* __restrict__ W,
                            unsigned short* __restrict__ T, const float* __restrict__ bias) {
    constexpr int PAIRS = DOUT / 2;
    __shared__ float xs[64 * DIN];
    __shared__ float wsm[DIN * DOUT];
    const int n0 = blockIdx.x * 64;
    for (int i = threadIdx.x; i < DIN * DOUT; i += 256) wsm[i] = W[i];
    if (IN_F32) {
        const float* X = (const float*)Xv;
        for (int i = threadIdx.x; i < 64 * DIN; i += 256) {
            int r = i / DIN, c = i - r * DIN;
            int node = n0 + r;
            xs[i] = (node < N_NODES) ? X[(size_t)node * DIN + c] : 0.f;
        }
    } else {
        const unsigned short* X = (const unsigned short*)Xv;
        for (int i = threadIdx.x; i < 64 * DIN; i += 256) {
            int r = i / DIN, c = i - r * DIN;
            int node = n0 + r;
            xs[i] = (node < N_NODES) ? bf2f(X[(size_t)node * DIN + c]) : 0.f;
        }
    }
    __syncthreads();
    unsigned int* Tu = (unsigned int*)T;
    for (int o = threadIdx.x; o < 64 * PAIRS; o += 256) {
        int r = o / PAIRS, jp = o - r * PAIRS;
        int node = n0 + r;
        if (node < N_NODES) {
            float a0 = 0.f, a1 = 0.f;
            const float* xr = xs + r * DIN;
#pragma unroll
            for (int k = 0; k < DIN; ++k) {
                float xv = xr[k];
                a0 = fmaf(xv, wsm[k * DOUT + 2 * jp], a0);
                a1 = fmaf(xv, wsm[k * DOUT + 2 * jp + 1], a1);
            }
            if (BIAS) { a0 += bias[2 * jp]; a1 += bias[2 * jp + 1]; }
            if (RELU) { a0 = lrelu(a0); a1 = lrelu(a1); }
            Tu[(size_t)node * PAIRS + jp] = ((unsigned int)f2bf(a1) << 16) | f2bf(a0);
        }
    }
}

// ============ CSR gather-aggregate (bf16 pairs): out[i,:] = sum T[adj,:] ============
template <int DOUT, bool BIAS, bool RELU>
__global__ void gather_agg_bf16(const unsigned short* __restrict__ T, const int* __restrict__ base,
                                const int* __restrict__ adj, const float* __restrict__ b,
                                unsigned short* __restrict__ out) {
    constexpr int PAIRS = DOUT / 2;                       // 8, 16, 25
    constexpr int LPN = (PAIRS <= 8) ? 8 : (PAIRS <= 16 ? 16 : 32);
    int gi = blockIdx.x * 256 + threadIdx.x;
    int node = gi / LPN;
    int j = gi & (LPN - 1);
    if (node >= N_NODES) return;
    if (j < PAIRS) {
        float a0 = 0.f, a1 = 0.f;
        int e0 = base[node], e1 = base[node + 1];
        const unsigned int* Tu = (const unsigned int*)T;
        for (int k = e0; k < e1; ++k) {
            int s = adj[k];
            unsigned int v = Tu[(size_t)s * PAIRS + j];
            a0 += __uint_as_float(v << 16);
            a1 += __uint_as_float(v & 0xFFFF0000u);
        }
        if (BIAS) { a0 += b[2 * j]; a1 += b[2 * j + 1]; }
        if (RELU) { a0 = lrelu(a0); a1 = lrelu(a1); }
        ((unsigned int*)out)[(size_t)node * PAIRS + j] = ((unsigned int)f2bf(a1) << 16) | f2bf(a0);
    }
}

// ============ BatchNorm stats (bf16 input) ============
__global__ void bn_partial_kernel(const unsigned short* __restrict__ H, float* __restrict__ sum,
                                  float* __restrict__ ssum) {
    int tid = threadIdx.x;
    int j = tid % 50;
    int sub = tid / 50;
    float s = 0.f, ss = 0.f;
    if (tid < 250) {
        for (int node = blockIdx.x * 5 + sub; node < N_NODES; node += gridDim.x * 5) {
            float v = bf2f(H[(size_t)node * 50 + j]);
            s += v;
            ss += v * v;
        }
    }
    __shared__ float ls[256], lss[256];
    ls[tid] = s;
    lss[tid] = ss;
    __syncthreads();
    if (tid < 50) {
        float a = ls[tid] + ls[tid + 50] + ls[tid + 100] + ls[tid + 150] + ls[tid + 200];
        float c = lss[tid] + lss[tid + 50] + lss[tid + 100] + lss[tid + 150] + lss[tid + 200];
        atomicAdd(&sum[tid], a);
        atomicAdd(&ssum[tid], c);
    }
}

__global__ void bn_finalize_kernel(const float* __restrict__ sum, const float* __restrict__ ssum,
                                   float* __restrict__ mu, float* __restrict__ rsig) {
    int j = threadIdx.x;
    if (j < 50) {
        float m = sum[j] / (float)N_NODES;
        float var = ssum[j] / (float)N_NODES - m * m;
        mu[j] = m;
        rsig[j] = rsqrtf(fmaxf(var, 0.f) + 1e-5f);
    }
}

// ============ BN apply + lrelu + global_add_pool ============
__global__ void pool_kernel(const unsigned short* __restrict__ H, const int* __restrict__ batch,
                            const float* __restrict__ mu, const float* __restrict__ rsig,
                            const float* __restrict__ gamma, const float* __restrict__ beta,
                            float* __restrict__ G) {
    int i = blockIdx.x * 256 + threadIdx.x;
    if (i >= N_NODES * 50) return;
    int node = i / 50;
    int j = i - node * 50;
    float v = (bf2f(H[i]) - mu[j]) * rsig[j] * gamma[j] + beta[j];
    v = lrelu(v);
    atomicAdd(&G[(size_t)batch[node] * 50 + j], v);
}

// ============ MLP head ============
__global__ void mlp_kernel(const float* __restrict__ G,
                           const float* __restrict__ fc1W, const float* __restrict__ fc1b,
                           const float* __restrict__ fc2W, const float* __restrict__ fc2b,
                           const float* __restrict__ fc3W, const float* __restrict__ fc3b,
                           float* __restrict__ out) {
    int g = blockIdx.x * blockDim.x + threadIdx.x;
    if (g >= N_GRAPHS) return;
    float a[50];
#pragma unroll
    for (int k = 0; k < 50; ++k) a[k] = G[g * 50 + k];
    float h1[30];
#pragma unroll
    for (int j = 0; j < 30; ++j) {
        float acc = fc1b[j];
#pragma unroll
        for (int k = 0; k < 50; ++k) acc = fmaf(a[k], fc1W[k * 30 + j], acc);
        h1[j] = lrelu(acc);
    }
    float h2[20];
#pragma unroll
    for (int j = 0; j < 20; ++j) {
        float acc = fc2b[j];
#pragma unroll
        for (int k = 0; k < 30; ++k) acc = fmaf(h1[k], fc2W[k * 20 + j], acc);
        h2[j] = lrelu(acc);
    }
    float z0 = fc3b[0], z1 = fc3b[1];
#pragma unroll
    for (int k = 0; k < 20; ++k) {
        z0 = fmaf(h2[k], fc3W[k * 2 + 0], z0);
        z1 = fmaf(h2[k], fc3W[k * 2 + 1], z1);
    }
    float m = fmaxf(z0, z1);
    float lse = m + logf(expf(z0 - m) + expf(z1 - m));
    out[g * 2 + 0] = z0 - lse;
    out[g * 2 + 1] = z1 - lse;
}

extern "C" void kernel_launch(void* const* d_in, const int* in_sizes, int n_in,
                              void* d_out, int out_size, void* d_ws, size_t ws_size,
                              hipStream_t stream) {
    const float* x     = (const float*)d_in[0];
    const int*   ei    = (const int*)d_in[1];
    const int*   batch = (const int*)d_in[2];
    const float* W1 = (const float*)d_in[3];  const float* b1 = (const float*)d_in[4];
    const float* W2 = (const float*)d_in[5];  const float* b2 = (const float*)d_in[6];
    const float* W3 = (const float*)d_in[7];  const float* b3 = (const float*)d_in[8];
    const float* W4 = (const float*)d_in[9];  const float* b4 = (const float*)d_in[10];
    const float* bng = (const float*)d_in[11]; const float* bnb = (const float*)d_in[12];
    const float* fc1W = (const float*)d_in[13]; const float* fc1b = (const float*)d_in[14];
    const float* fc2W = (const float*)d_in[15]; const float* fc2b = (const float*)d_in[16];
    const float* fc3W = (const float*)d_in[17]; const float* fc3b = (const float*)d_in[18];

    const int* src = ei;
    const int* dst = ei + N_EDGES;

    // ---- workspace layout ----
    char* w = (char*)d_ws;
    unsigned short* bufA = (unsigned short*)w;      w += (size_t)6400000 * 2;  // 12.8 MB
    unsigned short* bufB = (unsigned short*)w;      w += (size_t)6400000 * 2;  // 12.8 MB
    int*   adj  = (int*)w;                          w += (size_t)N_EDGES * 4;  // 6.4 MB
    int*   deg  = (int*)w;                          w += (size_t)N_NODES * 4;
    int*   cursor = (int*)w;                        w += (size_t)N_NODES * 4;
    int*   base = (int*)w;                          w += (size_t)(N_NODES + 1) * 4;
    int*   chunkSum = (int*)w;                      w += 512 * 4;
    float* bnsum = (float*)w;                       w += 64 * 4;
    float* bnssum = (float*)w;                      w += 64 * 4;
    float* mu   = (float*)w;                        w += 64 * 4;
    float* rsig = (float*)w;                        w += 64 * 4;
    float* G    = (float*)w;                        w += (size_t)N_GRAPHS * 50 * 4;

    dim3 blk(256);
    const int edgeBlocks = (N_EDGES + 255) / 256;
    const int mmBlocks = (N_NODES + 63) / 64;

    // ---- CSR build (by dst) ----
    hipMemsetAsync(deg, 0, (size_t)N_NODES * 4, stream);
    hipMemsetAsync(cursor, 0, (size_t)N_NODES * 4, stream);
    degree_kernel<<<edgeBlocks, blk, 0, stream>>>(dst, deg);
    scan_chunks_kernel<<<NCHUNKS, blk, 0, stream>>>(deg, base, chunkSum);
    scan_tops_kernel<<<1, 512, 0, stream>>>(chunkSum);
    add_offsets_kernel<<<(N_NODES + 255) / 256, blk, 0, stream>>>(base, chunkSum);
    fill_adj_kernel<<<edgeBlocks, blk, 0, stream>>>(src, dst, base, cursor, adj);

    // ---- L1: T1 = x @ W1 [128->16]; h1 = lrelu(agg(T1) + b1) ----
    matmul_bf16<128, 16, true, false, false><<<mmBlocks, blk, 0, stream>>>(x, W1, bufA, nullptr);
    gather_agg_bf16<16, true, true><<<(N_NODES * 8 + 255) / 256, blk, 0, stream>>>(bufA, base, adj, b1, bufB);

    // ---- L2: s2 = agg(h1); h2 = lrelu(s2 @ W2 + b2) [16->32] ----
    gather_agg_bf16<16, false, false><<<(N_NODES * 8 + 255) / 256, blk, 0, stream>>>(bufB, base, adj, nullptr, bufA);
    matmul_bf16<16, 32, false, true, true><<<mmBlocks, blk, 0, stream>>>(bufA, W2, bufB, b2);

    // ---- L3: s3 = agg(h2); h3 = lrelu(s3 @ W3 + b3) [32->64] ----
    gather_agg_bf16<32, false, false><<<(N_NODES * 16 + 255) / 256, blk, 0, stream>>>(bufB, base, adj, nullptr, bufA);
    matmul_bf16<32, 64, false, true, true><<<mmBlocks, blk, 0, stream>>>(bufA, W3, bufB, b3);

    // ---- L4: T4 = h3 @ W4 [64->50]; h4 = agg(T4) + b4 ----
    matmul_bf16<64, 50, false, false, false><<<mmBlocks, blk, 0, stream>>>(bufB, W4, bufA, nullptr);
    gather_agg_bf16<50, true, false><<<(N_NODES * 32 + 255) / 256, blk, 0, stream>>>(bufA, base, adj, b4, bufB);

    // ---- BatchNorm stats ----
    hipMemsetAsync(bnsum, 0, 128 * 4, stream);
    bn_partial_kernel<<<256, blk, 0, stream>>>(bufB, bnsum, bnssum);
    bn_finalize_kernel<<<1, 64, 0, stream>>>(bnsum, bnssum, mu, rsig);

    // ---- BN apply + lrelu + pool ----
    hipMemsetAsync(G, 0, (size_t)N_GRAPHS * 50 * 4, stream);
    pool_kernel<<<(N_NODES * 50 + 255) / 256, blk, 0, stream>>>(bufB, batch, mu, rsig, bng, bnb, G);

    // ---- MLP head ----
    mlp_kernel<<<1, 256, 0, stream>>>(G, fc1W, fc1b, fc2W, fc2b, fc3W, fc3b, (float*)d_out);
}

// Round 7
// 610.465 us; speedup vs baseline: 2.4595x; 1.1884x over previous
//
#include <hip/hip_runtime.h>

#define N_NODES 100000
#define N_EDGES 1600000
#define N_GRAPHS 256
#define NCHUNKS ((N_NODES + 255) / 256)   // 391

__device__ __forceinline__ float lrelu(float v) { return v > 0.f ? v : 0.01f * v; }

// bf16 storage helpers (RNE)
__device__ __forceinline__ unsigned short f2bf(float f) {
    unsigned int u = __float_as_uint(f);
    return (unsigned short)((u + 0x7FFFu + ((u >> 16) & 1u)) >> 16);
}
__device__ __forceinline__ float bf2f(unsigned short h) {
    return __uint_as_float(((unsigned int)h) << 16);
}

// ============ CSR build ============
__global__ void degree_kernel(const int* __restrict__ dst, int* __restrict__ deg) {
    int e = blockIdx.x * 256 + threadIdx.x;
    if (e < N_EDGES) atomicAdd(&deg[dst[e]], 1);
}

__global__ void scan_chunks_kernel(const int* __restrict__ deg, int* __restrict__ base,
                                   int* __restrict__ chunkSum) {
    __shared__ int s[256];
    int t = threadIdx.x;
    int i = blockIdx.x * 256 + t;
    int v = (i < N_NODES) ? deg[i] : 0;
    s[t] = v;
    __syncthreads();
    for (int off = 1; off < 256; off <<= 1) {
        int add = (t >= off) ? s[t - off] : 0;
        __syncthreads();
        s[t] += add;
        __syncthreads();
    }
    if (i < N_NODES) base[i + 1] = s[t];
    if (t == 255) chunkSum[blockIdx.x] = s[255];
    if (i == 0) base[0] = 0;
}

__global__ void scan_tops_kernel(int* __restrict__ chunkSum) {
    __shared__ int s[512];
    int t = threadIdx.x;
    s[t] = (t < NCHUNKS) ? chunkSum[t] : 0;
    __syncthreads();
    for (int off = 1; off < 512; off <<= 1) {
        int add = (t >= off) ? s[t - off] : 0;
        __syncthreads();
        s[t] += add;
        __syncthreads();
    }
    if (t < NCHUNKS) chunkSum[t] = s[t];
}

__global__ void add_offsets_kernel(int* __restrict__ base, const int* __restrict__ chunkSum) {
    int i = blockIdx.x * 256 + threadIdx.x;
    if (i < N_NODES) {
        int b = i / 256;
        if (b > 0) base[i + 1] += chunkSum[b - 1];
    }
}

__global__ void fill_adj_kernel(const int* __restrict__ src, const int* __restrict__ dst,
                                const int* __restrict__ base, int* __restrict__ cursor,
                                int* __restrict__ adj) {
    int e = blockIdx.x * 256 + threadIdx.x;
    if (e < N_EDGES) {
        int d = dst[e];
        int pos = atomicAdd(&cursor[d], 1);
        adj[base[d] + pos] = src[e];
    }
}

// ============ matmul: X[N,DIN] @ W[DIN,DOUT] -> T bf16, optional bias+lrelu ============
template <int DIN, int DOUT, bool IN_F32, bool BIAS, bool RELU>
__global__ void matmul_bf16(const void* __restrict__ Xv, const float* __restrict__ W,
                            unsigned short* __restrict__ T, const float* __restrict__ bias) {
    constexpr int PAIRS = DOUT / 2;
    __shared__ float xs[64 * DIN];
    __shared__ float wsm[DIN * DOUT];
    const int n0 = blockIdx.x * 64;
    for (int i = threadIdx.x; i < DIN * DOUT; i += 256) wsm[i] = W[i];
    if (IN_F32) {
        const float* X = (const float*)Xv;
        for (int i = threadIdx.x; i < 64 * DIN; i += 256) {
            int r = i / DIN, c = i - r * DIN;
            int node = n0 + r;
            xs[i] = (node < N_NODES) ? X[(size_t)node * DIN + c] : 0.f;
        }
    } else {
        const unsigned short* X = (const unsigned short*)Xv;
        for (int i = threadIdx.x; i < 64 * DIN; i += 256) {
            int r = i / DIN, c = i - r * DIN;
            int node = n0 + r;
            xs[i] = (node < N_NODES) ? bf2f(X[(size_t)node * DIN + c]) : 0.f;
        }
    }
    __syncthreads();
    unsigned int* Tu = (unsigned int*)T;
    for (int o = threadIdx.x; o < 64 * PAIRS; o += 256) {
        int r = o / PAIRS, jp = o - r * PAIRS;
        int node = n0 + r;
        if (node < N_NODES) {
            float a0 = 0.f, a1 = 0.f;
            const float* xr = xs + r * DIN;
#pragma unroll
            for (int k = 0; k < DIN; ++k) {
                float xv = xr[k];
                a0 = fmaf(xv, wsm[k * DOUT + 2 * jp], a0);
                a1 = fmaf(xv, wsm[k * DOUT + 2 * jp + 1], a1);
            }
            if (BIAS) { a0 += bias[2 * jp]; a1 += bias[2 * jp + 1]; }
            if (RELU) { a0 = lrelu(a0); a1 = lrelu(a1); }
            Tu[(size_t)node * PAIRS + jp] = ((unsigned int)f2bf(a1) << 16) | f2bf(a0);
        }
    }
}

// ============ CSR gather-aggregate (bf16 pairs), exact-PAIRS lane mapping ============
template <int DOUT, bool BIAS, bool RELU>
__global__ void gather_agg_bf16(const unsigned short* __restrict__ T, const int* __restrict__ base,
                                const int* __restrict__ adj, const float* __restrict__ b,
                                unsigned short* __restrict__ out) {
    constexpr int PAIRS = DOUT / 2;                       // 8, 16, 25
    int gi = blockIdx.x * 256 + threadIdx.x;
    int node = gi / PAIRS;                                // const div -> magic mul
    int j = gi - node * PAIRS;
    if (node >= N_NODES) return;
    float a0 = 0.f, a1 = 0.f;
    int e0 = base[node], e1 = base[node + 1];
    const unsigned int* Tu = (const unsigned int*)T;
    for (int k = e0; k < e1; ++k) {
        int s = adj[k];
        unsigned int v = Tu[(size_t)s * PAIRS + j];
        a0 += __uint_as_float(v << 16);
        a1 += __uint_as_float(v & 0xFFFF0000u);
    }
    if (BIAS) { a0 += b[2 * j]; a1 += b[2 * j + 1]; }
    if (RELU) { a0 = lrelu(a0); a1 = lrelu(a1); }
    ((unsigned int*)out)[(size_t)node * PAIRS + j] = ((unsigned int)f2bf(a1) << 16) | f2bf(a0);
}

// ============ BatchNorm stats (bf16 input) ============
__global__ void bn_partial_kernel(const unsigned short* __restrict__ H, float* __restrict__ sum,
                                  float* __restrict__ ssum) {
    int tid = threadIdx.x;
    int j = tid % 50;
    int sub = tid / 50;
    float s = 0.f, ss = 0.f;
    if (tid < 250) {
        for (int node = blockIdx.x * 5 + sub; node < N_NODES; node += gridDim.x * 5) {
            float v = bf2f(H[(size_t)node * 50 + j]);
            s += v;
            ss += v * v;
        }
    }
    __shared__ float ls[256], lss[256];
    ls[tid] = s;
    lss[tid] = ss;
    __syncthreads();
    if (tid < 50) {
        float a = ls[tid] + ls[tid + 50] + ls[tid + 100] + ls[tid + 150] + ls[tid + 200];
        float c = lss[tid] + lss[tid + 50] + lss[tid + 100] + lss[tid + 150] + lss[tid + 200];
        atomicAdd(&sum[tid], a);
        atomicAdd(&ssum[tid], c);
    }
}

__global__ void bn_finalize_kernel(const float* __restrict__ sum, const float* __restrict__ ssum,
                                   float* __restrict__ mu, float* __restrict__ rsig) {
    int j = threadIdx.x;
    if (j < 50) {
        float m = sum[j] / (float)N_NODES;
        float var = ssum[j] / (float)N_NODES - m * m;
        mu[j] = m;
        rsig[j] = rsqrtf(fmaxf(var, 0.f) + 1e-5f);
    }
}

// ============ graph boundary search (batch is sorted) ============
__global__ void find_bounds_kernel(const int* __restrict__ batch, int* __restrict__ bounds) {
    int g = blockIdx.x * blockDim.x + threadIdx.x;
    if (g > N_GRAPHS) return;
    int lo = 0, hi = N_NODES;
    while (lo < hi) {
        int mid = (lo + hi) >> 1;
        if (batch[mid] < g) lo = mid + 1; else hi = mid;
    }
    bounds[g] = lo;
}

// ============ BN apply + lrelu + segmented pool: one block per graph ============
__global__ void pool_seg_kernel(const unsigned short* __restrict__ H, const int* __restrict__ bounds,
                                const float* __restrict__ mu, const float* __restrict__ rsig,
                                const float* __restrict__ gamma, const float* __restrict__ beta,
                                float* __restrict__ G) {
    int g = blockIdx.x;
    int s = bounds[g], e = bounds[g + 1];
    int tid = threadIdx.x;
    int j = tid % 50;
    int sub = tid / 50;     // 0..4 for tid<250
    float acc = 0.f;
    if (tid < 250) {
        float scale = rsig[j] * gamma[j];
        float shift = beta[j] - mu[j] * scale;
        for (int n = s + sub; n < e; n += 5) {
            float v = fmaf(bf2f(H[(size_t)n * 50 + j]), scale, shift);
            acc += lrelu(v);
        }
    }
    __shared__ float ls[256];
    ls[tid] = acc;
    __syncthreads();
    if (tid < 50) {
        G[g * 50 + tid] = ls[tid] + ls[tid + 50] + ls[tid + 100] + ls[tid + 150] + ls[tid + 200];
    }
}

// ============ MLP head ============
__global__ void mlp_kernel(const float* __restrict__ G,
                           const float* __restrict__ fc1W, const float* __restrict__ fc1b,
                           const float* __restrict__ fc2W, const float* __restrict__ fc2b,
                           const float* __restrict__ fc3W, const float* __restrict__ fc3b,
                           float* __restrict__ out) {
    int g = blockIdx.x * blockDim.x + threadIdx.x;
    if (g >= N_GRAPHS) return;
    float a[50];
#pragma unroll
    for (int k = 0; k < 50; ++k) a[k] = G[g * 50 + k];
    float h1[30];
#pragma unroll
    for (int j = 0; j < 30; ++j) {
        float acc = fc1b[j];
#pragma unroll
        for (int k = 0; k < 50; ++k) acc = fmaf(a[k], fc1W[k * 30 + j], acc);
        h1[j] = lrelu(acc);
    }
    float h2[20];
#pragma unroll
    for (int j = 0; j < 20; ++j) {
        float acc = fc2b[j];
#pragma unroll
        for (int k = 0; k < 30; ++k) acc = fmaf(h1[k], fc2W[k * 20 + j], acc);
        h2[j] = lrelu(acc);
    }
    float z0 = fc3b[0], z1 = fc3b[1];
#pragma unroll
    for (int k = 0; k < 20; ++k) {
        z0 = fmaf(h2[k], fc3W[k * 2 + 0], z0);
        z1 = fmaf(h2[k], fc3W[k * 2 + 1], z1);
    }
    float m = fmaxf(z0, z1);
    float lse = m + logf(expf(z0 - m) + expf(z1 - m));
    out[g * 2 + 0] = z0 - lse;
    out[g * 2 + 1] = z1 - lse;
}

extern "C" void kernel_launch(void* const* d_in, const int* in_sizes, int n_in,
                              void* d_out, int out_size, void* d_ws, size_t ws_size,
                              hipStream_t stream) {
    const float* x     = (const float*)d_in[0];
    const int*   ei    = (const int*)d_in[1];
    const int*   batch = (const int*)d_in[2];
    const float* W1 = (const float*)d_in[3];  const float* b1 = (const float*)d_in[4];
    const float* W2 = (const float*)d_in[5];  const float* b2 = (const float*)d_in[6];
    const float* W3 = (const float*)d_in[7];  const float* b3 = (const float*)d_in[8];
    const float* W4 = (const float*)d_in[9];  const float* b4 = (const float*)d_in[10];
    const float* bng = (const float*)d_in[11]; const float* bnb = (const float*)d_in[12];
    const float* fc1W = (const float*)d_in[13]; const float* fc1b = (const float*)d_in[14];
    const float* fc2W = (const float*)d_in[15]; const float* fc2b = (const float*)d_in[16];
    const float* fc3W = (const float*)d_in[17]; const float* fc3b = (const float*)d_in[18];

    const int* src = ei;
    const int* dst = ei + N_EDGES;

    // ---- workspace layout ----
    char* w = (char*)d_ws;
    unsigned short* bufA = (unsigned short*)w;      w += (size_t)6400000 * 2;  // 12.8 MB
    unsigned short* bufB = (unsigned short*)w;      w += (size_t)6400000 * 2;  // 12.8 MB
    int*   adj  = (int*)w;                          w += (size_t)N_EDGES * 4;  // 6.4 MB
    int*   deg  = (int*)w;                          w += (size_t)N_NODES * 4;
    int*   cursor = (int*)w;                        w += (size_t)N_NODES * 4;
    int*   base = (int*)w;                          w += (size_t)(N_NODES + 1) * 4;
    int*   chunkSum = (int*)w;                      w += 512 * 4;
    float* bnsum = (float*)w;                       w += 64 * 4;
    float* bnssum = (float*)w;                      w += 64 * 4;
    float* mu   = (float*)w;                        w += 64 * 4;
    float* rsig = (float*)w;                        w += 64 * 4;
    int*   bounds = (int*)w;                        w += (N_GRAPHS + 1) * 4;
    float* G    = (float*)w;                        w += (size_t)N_GRAPHS * 50 * 4;

    dim3 blk(256);
    const int edgeBlocks = (N_EDGES + 255) / 256;
    const int mmBlocks = (N_NODES + 63) / 64;

    // ---- CSR build (by dst) ----
    hipMemsetAsync(deg, 0, (size_t)N_NODES * 4, stream);
    hipMemsetAsync(cursor, 0, (size_t)N_NODES * 4, stream);
    degree_kernel<<<edgeBlocks, blk, 0, stream>>>(dst, deg);
    scan_chunks_kernel<<<NCHUNKS, blk, 0, stream>>>(deg, base, chunkSum);
    scan_tops_kernel<<<1, 512, 0, stream>>>(chunkSum);
    add_offsets_kernel<<<(N_NODES + 255) / 256, blk, 0, stream>>>(base, chunkSum);
    fill_adj_kernel<<<edgeBlocks, blk, 0, stream>>>(src, dst, base, cursor, adj);
    find_bounds_kernel<<<2, 256, 0, stream>>>(batch, bounds);

    // ---- L1: T1 = x @ W1 [128->16]; h1 = lrelu(agg(T1) + b1) ----
    matmul_bf16<128, 16, true, false, false><<<mmBlocks, blk, 0, stream>>>(x, W1, bufA, nullptr);
    gather_agg_bf16<16, true, true><<<(N_NODES * 8 + 255) / 256, blk, 0, stream>>>(bufA, base, adj, b1, bufB);

    // ---- L2: s2 = agg(h1); h2 = lrelu(s2 @ W2 + b2) [16->32] ----
    gather_agg_bf16<16, false, false><<<(N_NODES * 8 + 255) / 256, blk, 0, stream>>>(bufB, base, adj, nullptr, bufA);
    matmul_bf16<16, 32, false, true, true><<<mmBlocks, blk, 0, stream>>>(bufA, W2, bufB, b2);

    // ---- L3: s3 = agg(h2); h3 = lrelu(s3 @ W3 + b3) [32->64] ----
    gather_agg_bf16<32, false, false><<<(N_NODES * 16 + 255) / 256, blk, 0, stream>>>(bufB, base, adj, nullptr, bufA);
    matmul_bf16<32, 64, false, true, true><<<mmBlocks, blk, 0, stream>>>(bufA, W3, bufB, b3);

    // ---- L4: T4 = h3 @ W4 [64->50]; h4 = agg(T4) + b4 ----
    matmul_bf16<64, 50, false, false, false><<<mmBlocks, blk, 0, stream>>>(bufB, W4, bufA, nullptr);
    gather_agg_bf16<50, true, false><<<(N_NODES * 25 + 255) / 256, blk, 0, stream>>>(bufA, base, adj, b4, bufB);

    // ---- BatchNorm stats ----
    hipMemsetAsync(bnsum, 0, 128 * 4, stream);
    bn_partial_kernel<<<256, blk, 0, stream>>>(bufB, bnsum, bnssum);
    bn_finalize_kernel<<<1, 64, 0, stream>>>(bnsum, bnssum, mu, rsig);

    // ---- BN apply + lrelu + segmented pool (no atomics) ----
    pool_seg_kernel<<<N_GRAPHS, blk, 0, stream>>>(bufB, bounds, mu, rsig, bng, bnb, G);

    // ---- MLP head ----
    mlp_kernel<<<1, 256, 0, stream>>>(G, fc1W, fc1b, fc2W, fc2b, fc3W, fc3b, (float*)d_out);
}

// Round 9
// 571.627 us; speedup vs baseline: 2.6266x; 1.0679x over previous
//
#include <hip/hip_runtime.h>

#define N_NODES 100000
#define N_EDGES 1600000
#define N_GRAPHS 256
#define NCHUNKS ((N_NODES + 255) / 256)   // 391
#define RANGE_PER_XCD 12500               // 100000 / 8

__device__ __forceinline__ float lrelu(float v) { return v > 0.f ? v : 0.01f * v; }

// bf16 storage helpers (RNE)
__device__ __forceinline__ unsigned short f2bf(float f) {
    unsigned int u = __float_as_uint(f);
    return (unsigned short)((u + 0x7FFFu + ((u >> 16) & 1u)) >> 16);
}
__device__ __forceinline__ float bf2f(unsigned short h) {
    return __uint_as_float(((unsigned int)h) << 16);
}

// ============ CSR build ============
__global__ void degree_kernel(const int* __restrict__ dst, int* __restrict__ deg) {
    int e = blockIdx.x * 256 + threadIdx.x;
    if (e < N_EDGES) atomicAdd(&deg[dst[e]], 1);
}

__global__ void scan_chunks_kernel(const int* __restrict__ deg, int* __restrict__ base,
                                   int* __restrict__ chunkSum) {
    __shared__ int s[256];
    int t = threadIdx.x;
    int i = blockIdx.x * 256 + t;
    int v = (i < N_NODES) ? deg[i] : 0;
    s[t] = v;
    __syncthreads();
    for (int off = 1; off < 256; off <<= 1) {
        int add = (t >= off) ? s[t - off] : 0;
        __syncthreads();
        s[t] += add;
        __syncthreads();
    }
    if (i < N_NODES) base[i + 1] = s[t];
    if (t == 255) chunkSum[blockIdx.x] = s[255];
    if (i == 0) base[0] = 0;
}

__global__ void scan_tops_kernel(int* __restrict__ chunkSum) {
    __shared__ int s[512];
    int t = threadIdx.x;
    s[t] = (t < NCHUNKS) ? chunkSum[t] : 0;
    __syncthreads();
    for (int off = 1; off < 512; off <<= 1) {
        int add = (t >= off) ? s[t - off] : 0;
        __syncthreads();
        s[t] += add;
        __syncthreads();
    }
    if (t < NCHUNKS) chunkSum[t] = s[t];
}

__global__ void add_offsets_kernel(int* __restrict__ base, const int* __restrict__ chunkSum) {
    int i = blockIdx.x * 256 + threadIdx.x;
    if (i < N_NODES) {
        int b = i / 256;
        if (b > 0) base[i + 1] += chunkSum[b - 1];
    }
}

// XCD-range-partitioned scatter: block b handles edge chunk (b>>3), but only
// edges whose dst lies in node range (b&7)*12500..+12500. With the round-robin
// blockIdx->XCD dispatch, each adj region is dirtied by a single XCD's L2,
// collapsing write amplification. Correct regardless of actual placement.
__global__ void fill_adj_xcd(const int* __restrict__ src, const int* __restrict__ dst,
                             const int* __restrict__ base, int* __restrict__ cursor,
                             int* __restrict__ adj) {
    int lo = (blockIdx.x & 7) * RANGE_PER_XCD;
    int hi = lo + RANGE_PER_XCD;
    int e0 = (blockIdx.x >> 3) * 1024 + threadIdx.x;
#pragma unroll
    for (int i = 0; i < 4; ++i) {
        int e = e0 + i * 256;
        if (e < N_EDGES) {
            int d = dst[e];
            if (d >= lo && d < hi) {
                int pos = atomicAdd(&cursor[d], 1);
                adj[base[d] + pos] = src[e];
            }
        }
    }
}

// ============ matmul: X[N,DIN] @ W[DIN,DOUT] -> T bf16, optional bias+lrelu ============
template <int DIN, int DOUT, bool IN_F32, bool BIAS, bool RELU>
__global__ void matmul_bf16(const void* __restrict__ Xv, const float* __restrict__ W,
                            unsigned short* __restrict__ T, const float* __restrict__ bias) {
    constexpr int PAIRS = DOUT / 2;
    __shared__ float xs[64 * DIN];
    __shared__ float wsm[DIN * DOUT];
    const int n0 = blockIdx.x * 64;
    const bool full = (n0 + 64 <= N_NODES);
    for (int i = threadIdx.x; i < DIN * DOUT; i += 256) wsm[i] = W[i];
    if (IN_F32) {
        const float4* X4 = (const float4*)Xv;
        constexpr int V = DIN / 4;   // float4 per row
        for (int i = threadIdx.x; i < 64 * V; i += 256) {
            int r = i / V, c = i - r * V;
            int node = n0 + r;
            float4 v;
            if (full || node < N_NODES) v = X4[(size_t)node * V + c];
            else v = make_float4(0.f, 0.f, 0.f, 0.f);
            ((float4*)xs)[i] = v;
        }
    } else {
        const unsigned int* X2 = (const unsigned int*)Xv;   // 2 bf16 per uint
        constexpr int V = DIN / 2;
        for (int i = threadIdx.x; i < 64 * V; i += 256) {
            int r = i / V, c = i - r * V;
            int node = n0 + r;
            unsigned int v = (full || node < N_NODES) ? X2[(size_t)node * V + c] : 0u;
            xs[r * DIN + 2 * c]     = __uint_as_float(v << 16);
            xs[r * DIN + 2 * c + 1] = __uint_as_float(v & 0xFFFF0000u);
        }
    }
    __syncthreads();
    unsigned int* Tu = (unsigned int*)T;
    for (int o = threadIdx.x; o < 64 * PAIRS; o += 256) {
        int r = o / PAIRS, jp = o - r * PAIRS;
        int node = n0 + r;
        if (node < N_NODES) {
            float a0 = 0.f, a1 = 0.f;
            const float* xr = xs + r * DIN;
#pragma unroll
            for (int k = 0; k < DIN; ++k) {
                float xv = xr[k];
                a0 = fmaf(xv, wsm[k * DOUT + 2 * jp], a0);
                a1 = fmaf(xv, wsm[k * DOUT + 2 * jp + 1], a1);
            }
            if (BIAS) { a0 += bias[2 * jp]; a1 += bias[2 * jp + 1]; }
            if (RELU) { a0 = lrelu(a0); a1 = lrelu(a1); }
            Tu[(size_t)node * PAIRS + jp] = ((unsigned int)f2bf(a1) << 16) | f2bf(a0);
        }
    }
}

// ============ CSR gather-aggregate (bf16 pairs), exact-PAIRS lane mapping ============
template <int DOUT, bool BIAS, bool RELU>
__global__ void gather_agg_bf16(const unsigned short* __restrict__ T, const int* __restrict__ base,
                                const int* __restrict__ adj, const float* __restrict__ b,
                                unsigned short* __restrict__ out) {
    constexpr int PAIRS = DOUT / 2;                       // 8, 16, 25
    int gi = blockIdx.x * 256 + threadIdx.x;
    int node = gi / PAIRS;                                // const div -> magic mul
    int j = gi - node * PAIRS;
    if (node >= N_NODES) return;
    float a0 = 0.f, a1 = 0.f;
    int e0 = base[node], e1 = base[node + 1];
    const unsigned int* Tu = (const unsigned int*)T;
    for (int k = e0; k < e1; ++k) {
        int s = adj[k];
        unsigned int v = Tu[(size_t)s * PAIRS + j];
        a0 += __uint_as_float(v << 16);
        a1 += __uint_as_float(v & 0xFFFF0000u);
    }
    if (BIAS) { a0 += b[2 * j]; a1 += b[2 * j + 1]; }
    if (RELU) { a0 = lrelu(a0); a1 = lrelu(a1); }
    ((unsigned int*)out)[(size_t)node * PAIRS + j] = ((unsigned int)f2bf(a1) << 16) | f2bf(a0);
}

// ============ BatchNorm stats (bf16 input) ============
__global__ void bn_partial_kernel(const unsigned short* __restrict__ H, float* __restrict__ sum,
                                  float* __restrict__ ssum) {
    int tid = threadIdx.x;
    int j = tid % 50;
    int sub = tid / 50;
    float s = 0.f, ss = 0.f;
    if (tid < 250) {
        for (int node = blockIdx.x * 5 + sub; node < N_NODES; node += gridDim.x * 5) {
            float v = bf2f(H[(size_t)node * 50 + j]);
            s += v;
            ss += v * v;
        }
    }
    __shared__ float ls[256], lss[256];
    ls[tid] = s;
    lss[tid] = ss;
    __syncthreads();
    if (tid < 50) {
        float a = ls[tid] + ls[tid + 50] + ls[tid + 100] + ls[tid + 150] + ls[tid + 200];
        float c = lss[tid] + lss[tid + 50] + lss[tid + 100] + lss[tid + 150] + lss[tid + 200];
        atomicAdd(&sum[tid], a);
        atomicAdd(&ssum[tid], c);
    }
}

__global__ void bn_finalize_kernel(const float* __restrict__ sum, const float* __restrict__ ssum,
                                   float* __restrict__ mu, float* __restrict__ rsig) {
    int j = threadIdx.x;
    if (j < 50) {
        float m = sum[j] / (float)N_NODES;
        float var = ssum[j] / (float)N_NODES - m * m;
        mu[j] = m;
        rsig[j] = rsqrtf(fmaxf(var, 0.f) + 1e-5f);
    }
}

// ============ graph boundary search (batch is sorted) ============
__global__ void find_bounds_kernel(const int* __restrict__ batch, int* __restrict__ bounds) {
    int g = blockIdx.x * blockDim.x + threadIdx.x;
    if (g > N_GRAPHS) return;
    int lo = 0, hi = N_NODES;
    while (lo < hi) {
        int mid = (lo + hi) >> 1;
        if (batch[mid] < g) lo = mid + 1; else hi = mid;
    }
    bounds[g] = lo;
}

// ============ BN apply + lrelu + segmented pool: one block per graph ============
__global__ void pool_seg_kernel(const unsigned short* __restrict__ H, const int* __restrict__ bounds,
                                const float* __restrict__ mu, const float* __restrict__ rsig,
                                const float* __restrict__ gamma, const float* __restrict__ beta,
                                float* __restrict__ G) {
    int g = blockIdx.x;
    int s = bounds[g], e = bounds[g + 1];
    int tid = threadIdx.x;
    int j = tid % 50;
    int sub = tid / 50;     // 0..4 for tid<250
    float acc = 0.f;
    if (tid < 250) {
        float scale = rsig[j] * gamma[j];
        float shift = beta[j] - mu[j] * scale;
        for (int n = s + sub; n < e; n += 5) {
            float v = fmaf(bf2f(H[(size_t)n * 50 + j]), scale, shift);
            acc += lrelu(v);
        }
    }
    __shared__ float ls[256];
    ls[tid] = acc;
    __syncthreads();
    if (tid < 50) {
        G[g * 50 + tid] = ls[tid] + ls[tid + 50] + ls[tid + 100] + ls[tid + 150] + ls[tid + 200];
    }
}

// ============ MLP head ============
__global__ void mlp_kernel(const float* __restrict__ G,
                           const float* __restrict__ fc1W, const float* __restrict__ fc1b,
                           const float* __restrict__ fc2W, const float* __restrict__ fc2b,
                           const float* __restrict__ fc3W, const float* __restrict__ fc3b,
                           float* __restrict__ out) {
    int g = blockIdx.x * blockDim.x + threadIdx.x;
    if (g >= N_GRAPHS) return;
    float a[50];
#pragma unroll
    for (int k = 0; k < 50; ++k) a[k] = G[g * 50 + k];
    float h1[30];
#pragma unroll
    for (int j = 0; j < 30; ++j) {
        float acc = fc1b[j];
#pragma unroll
        for (int k = 0; k < 50; ++k) acc = fmaf(a[k], fc1W[k * 30 + j], acc);
        h1[j] = lrelu(acc);
    }
    float h2[20];
#pragma unroll
    for (int j = 0; j < 20; ++j) {
        float acc = fc2b[j];
#pragma unroll
        for (int k = 0; k < 30; ++k) acc = fmaf(h1[k], fc2W[k * 20 + j], acc);
        h2[j] = lrelu(acc);
    }
    float z0 = fc3b[0], z1 = fc3b[1];
#pragma unroll
    for (int k = 0; k < 20; ++k) {
        z0 = fmaf(h2[k], fc3W[k * 2 + 0], z0);
        z1 = fmaf(h2[k], fc3W[k * 2 + 1], z1);
    }
    float m = fmaxf(z0, z1);
    float lse = m + logf(expf(z0 - m) + expf(z1 - m));
    out[g * 2 + 0] = z0 - lse;
    out[g * 2 + 1] = z1 - lse;
}

extern "C" void kernel_launch(void* const* d_in, const int* in_sizes, int n_in,
                              void* d_out, int out_size, void* d_ws, size_t ws_size,
                              hipStream_t stream) {
    const float* x     = (const float*)d_in[0];
    const int*   ei    = (const int*)d_in[1];
    const int*   batch = (const int*)d_in[2];
    const float* W1 = (const float*)d_in[3];  const float* b1 = (const float*)d_in[4];
    const float* W2 = (const float*)d_in[5];  const float* b2 = (const float*)d_in[6];
    const float* W3 = (const float*)d_in[7];  const float* b3 = (const float*)d_in[8];
    const float* W4 = (const float*)d_in[9];  const float* b4 = (const float*)d_in[10];
    const float* bng = (const float*)d_in[11]; const float* bnb = (const float*)d_in[12];
    const float* fc1W = (const float*)d_in[13]; const float* fc1b = (const float*)d_in[14];
    const float* fc2W = (const float*)d_in[15]; const float* fc2b = (const float*)d_in[16];
    const float* fc3W = (const float*)d_in[17]; const float* fc3b = (const float*)d_in[18];

    const int* src = ei;
    const int* dst = ei + N_EDGES;

    // ---- workspace layout ----
    char* w = (char*)d_ws;
    unsigned short* bufA = (unsigned short*)w;      w += (size_t)6400000 * 2;  // 12.8 MB
    unsigned short* bufB = (unsigned short*)w;      w += (size_t)6400000 * 2;  // 12.8 MB
    int*   adj  = (int*)w;                          w += (size_t)N_EDGES * 4;  // 6.4 MB
    int*   deg  = (int*)w;                          w += (size_t)N_NODES * 4;
    int*   cursor = (int*)w;                        w += (size_t)N_NODES * 4;
    int*   base = (int*)w;                          w += (size_t)(N_NODES + 1) * 4;
    int*   chunkSum = (int*)w;                      w += 512 * 4;
    float* bnsum = (float*)w;                       w += 64 * 4;
    float* bnssum = (float*)w;                      w += 64 * 4;
    float* mu   = (float*)w;                        w += 64 * 4;
    float* rsig = (float*)w;                        w += 64 * 4;
    int*   bounds = (int*)w;                        w += (N_GRAPHS + 1) * 4;
    float* G    = (float*)w;                        w += (size_t)N_GRAPHS * 50 * 4;

    dim3 blk(256);
    const int edgeBlocks = (N_EDGES + 255) / 256;
    const int mmBlocks = (N_NODES + 63) / 64;

    // ---- CSR build (by dst) ----
    hipMemsetAsync(deg, 0, (size_t)N_NODES * 4, stream);
    hipMemsetAsync(cursor, 0, (size_t)N_NODES * 4, stream);
    degree_kernel<<<edgeBlocks, blk, 0, stream>>>(dst, deg);
    scan_chunks_kernel<<<NCHUNKS, blk, 0, stream>>>(deg, base, chunkSum);
    scan_tops_kernel<<<1, 512, 0, stream>>>(chunkSum);
    add_offsets_kernel<<<(N_NODES + 255) / 256, blk, 0, stream>>>(base, chunkSum);
    fill_adj_xcd<<<8 * ((N_EDGES + 1023) / 1024), blk, 0, stream>>>(src, dst, base, cursor, adj);
    find_bounds_kernel<<<2, 256, 0, stream>>>(batch, bounds);

    // ---- L1: T1 = x @ W1 [128->16]; h1 = lrelu(agg(T1) + b1) ----
    matmul_bf16<128, 16, true, false, false><<<mmBlocks, blk, 0, stream>>>(x, W1, bufA, nullptr);
    gather_agg_bf16<16, true, true><<<(N_NODES * 8 + 255) / 256, blk, 0, stream>>>(bufA, base, adj, b1, bufB);

    // ---- L2: s2 = agg(h1); h2 = lrelu(s2 @ W2 + b2) [16->32] ----
    gather_agg_bf16<16, false, false><<<(N_NODES * 8 + 255) / 256, blk, 0, stream>>>(bufB, base, adj, nullptr, bufA);
    matmul_bf16<16, 32, false, true, true><<<mmBlocks, blk, 0, stream>>>(bufA, W2, bufB, b2);

    // ---- L3: s3 = agg(h2); h3 = lrelu(s3 @ W3 + b3) [32->64] ----
    gather_agg_bf16<32, false, false><<<(N_NODES * 16 + 255) / 256, blk, 0, stream>>>(bufB, base, adj, nullptr, bufA);
    matmul_bf16<32, 64, false, true, true><<<mmBlocks, blk, 0, stream>>>(bufA, W3, bufB, b3);

    // ---- L4: T4 = h3 @ W4 [64->50]; h4 = agg(T4) + b4 ----
    matmul_bf16<64, 50, false, false, false><<<mmBlocks, blk, 0, stream>>>(bufB, W4, bufA, nullptr);
    gather_agg_bf16<50, true, false><<<(N_NODES * 25 + 255) / 256, blk, 0, stream>>>(bufA, base, adj, b4, bufB);

    // ---- BatchNorm stats ----
    hipMemsetAsync(bnsum, 0, 128 * 4, stream);
    bn_partial_kernel<<<256, blk, 0, stream>>>(bufB, bnsum, bnssum);
    bn_finalize_kernel<<<1, 64, 0, stream>>>(bnsum, bnssum, mu, rsig);

    // ---- BN apply + lrelu + segmented pool (no atomics) ----
    pool_seg_kernel<<<N_GRAPHS, blk, 0, stream>>>(bufB, bounds, mu, rsig, bng, bnb, G);

    // ---- MLP head ----
    mlp_kernel<<<1, 256, 0, stream>>>(G, fc1W, fc1b, fc2W, fc2b, fc3W, fc3b, (float*)d_out);
}